// Round 6
// baseline (149.588 us; speedup 1.0000x reference)
//
#include <hip/hip_runtime.h>
#include <hip/hip_bf16.h>

// SSIM loss, round 13: TWO-PASS DENSE LAYOUT.
// r7/r10/r11/r12 (4 different staging schemes, depths 1-2, 8-16 waves/CU)
// all capped at ~3.6-3.9 GB/s/CU. Surviving invariant: comb-shaped demand
// (128-512B teeth on 2KB pitch from ~2048 drifting streams). m13 copy
// (6.3 TB/s) and RMSNorm (4.9 TB/s) read SOLID runs. Fix = layout:
//   pass1: read full 512-col rows (1KB solid/inst, sequential), feature+
//          hblur MFMA (verbatim hproc math), write hblur features
//          tile-blocked+transposed so pass2's reads are contiguous.
//   pass2: r12 vstep/band/SSIM/reduce verbatim; staging = gload_lds of
//          CONTIGUOUS 1KB blocks into per-wave 8-tile ring, counted
//          vmcnt(8) (~4 tiles in flight), zero barriers.
// Pass1 doubles as an embedded m13-shaped probe: its counter row alone
// confirms/refutes the density theory. Fallback to r12 kernel if ws small.

typedef float  f32x4  __attribute__((ext_vector_type(4)));
typedef short  short8 __attribute__((ext_vector_type(8)));
typedef short  short4v __attribute__((ext_vector_type(4)));

__device__ __forceinline__ short bf16s(float x) {
    __hip_bfloat16 h = __float2bfloat16(x);
    return __builtin_bit_cast(short, h);
}
__device__ __forceinline__ float bf16f(float x) {
    unsigned u = (unsigned)__builtin_bit_cast(unsigned short,
                                              __float2bfloat16(x)) << 16;
    return __builtin_bit_cast(float, u);
}
__device__ __forceinline__ void gload16(const void* g, void* lds) {
    __builtin_amdgcn_global_load_lds(g, lds, 16, 0, 0);
}

#define WAITV8 asm volatile("s_waitcnt vmcnt(8)" ::: "memory")
#define WAITV6 asm volatile("s_waitcnt vmcnt(6)" ::: "memory")
#define WAITV4 asm volatile("s_waitcnt vmcnt(4)" ::: "memory")
#define WAITV2 asm volatile("s_waitcnt vmcnt(2)" ::: "memory")
#define WAITV0 asm volatile("s_waitcnt vmcnt(0)" ::: "memory")

#define SSIM_W_INIT const float W[11] = { \
    0.00102840f, 0.00759876f, 0.03600077f, 0.10936070f, 0.21300554f, \
    0.26601173f, \
    0.21300554f, 0.10936070f, 0.03600077f, 0.00759876f, 0.00102840f}

#define BW_INIT short8 bw; _Pragma("unroll") \
    for (int j = 0; j < 8; ++j) { \
        const int d = quad * 8 + j - n - 3; \
        bw[j] = bf16s((d >= 0 && d <= 10) ? W[d] : 0.f); \
    }

// ============================ PASS 1: hblur =============================
// grid 1024 = 32 img x 32 slabs (16 rows x 512 cols each).
// feat layout: [img][stripe32][tile32] blocks of 1024 shorts (2KB):
//   [grp2][feat4][col16][slot8] bf16  (grp = rows 8g..8g+7 of the tile)
__global__ __launch_bounds__(256, 2)
void ssim_hblur(const float* __restrict__ pred, const float* __restrict__ targ,
                unsigned short* __restrict__ feat) {
    SSIM_W_INIT;
    __shared__ __align__(16) short featLds[4][16][72][8];  // 73,728 B

    const int w = threadIdx.x >> 6, L = threadIdx.x & 63;
    const int n = L & 15, quad = L >> 4;
    const int img = blockIdx.x >> 5, T = blockIdx.x & 31;

    // zero granules 0 (cols [-8,0)) and 65 (cols [512,520))
    if (threadIdx.x < 128) {
        const int f = threadIdx.x >> 5, r = (threadIdx.x >> 1) & 15;
        const int gz = (threadIdx.x & 1) ? 65 : 0;
        const short8 z = {0, 0, 0, 0, 0, 0, 0, 0};
        *(short8*)&featLds[f][r][gz ^ (r & 7)][0] = z;
    }

    BW_INIT;
    const f32x4 zc = {0.f, 0.f, 0.f, 0.f};

    // loads: wave w owns rows 16T+4w..+3; inst = 1KB solid (lane L at 4L)
    const size_t rowbase = (size_t)img * 262144 + (size_t)(16 * T + w * 4) * 512;
    const float* pr = pred + rowbase + 4 * L;
    const float* tr = targ + rowbase + 4 * L;
    const f32x4 pA0 = *(const f32x4*)(pr);
    const f32x4 pB0 = *(const f32x4*)(pr + 256);
    const f32x4 tA0 = *(const f32x4*)(tr);
    const f32x4 tB0 = *(const f32x4*)(tr + 256);
    const f32x4 pA1 = *(const f32x4*)(pr + 512);
    const f32x4 pB1 = *(const f32x4*)(pr + 768);
    const f32x4 tA1 = *(const f32x4*)(tr + 512);
    const f32x4 tB1 = *(const f32x4*)(tr + 768);
    const f32x4 pA2 = *(const f32x4*)(pr + 1024);
    const f32x4 pB2 = *(const f32x4*)(pr + 1280);
    const f32x4 tA2 = *(const f32x4*)(tr + 1024);
    const f32x4 tB2 = *(const f32x4*)(tr + 1280);
    const f32x4 pA3 = *(const f32x4*)(pr + 1536);
    const f32x4 pB3 = *(const f32x4*)(pr + 1792);
    const f32x4 tA3 = *(const f32x4*)(tr + 1536);
    const f32x4 tB3 = *(const f32x4*)(tr + 1792);

    // lane L covers cols [4L,4L+4) (half A, granule 1+(L>>1), half L&1)
    // and cols [256+4L,...) (half B, granule 33+(L>>1)).
    const int gA = 1 + (L >> 1), gB = 33 + (L >> 1), hh = (L & 1) * 4;

#define P1ROW(k, PV, TV, QV, UV)                                          \
    {                                                                     \
        const int r = w * 4 + k;                                          \
        const int m = r & 7;                                              \
        short4v s0, s1, s2, s3, q0, q1, q2, q3;                           \
        _Pragma("unroll") for (int j = 0; j < 4; ++j) {                   \
            const float p = PV[j], t = TV[j];                             \
            const float u = p + t, v = p - t;                             \
            s0[j] = bf16s(p); s1[j] = bf16s(t);                           \
            s2[j] = bf16s(u * u); s3[j] = bf16s(v * v);                   \
            const float p2 = QV[j], t2 = UV[j];                           \
            const float u2 = p2 + t2, v2 = p2 - t2;                       \
            q0[j] = bf16s(p2); q1[j] = bf16s(t2);                         \
            q2[j] = bf16s(u2 * u2); q3[j] = bf16s(v2 * v2);               \
        }                                                                 \
        *(short4v*)&featLds[0][r][gA ^ m][hh] = s0;                       \
        *(short4v*)&featLds[1][r][gA ^ m][hh] = s1;                       \
        *(short4v*)&featLds[2][r][gA ^ m][hh] = s2;                       \
        *(short4v*)&featLds[3][r][gA ^ m][hh] = s3;                       \
        *(short4v*)&featLds[0][r][gB ^ m][hh] = q0;                       \
        *(short4v*)&featLds[1][r][gB ^ m][hh] = q1;                       \
        *(short4v*)&featLds[2][r][gB ^ m][hh] = q2;                       \
        *(short4v*)&featLds[3][r][gB ^ m][hh] = q3;                       \
    }
    P1ROW(0, pA0, tA0, pB0, tB0)
    P1ROW(1, pA1, tA1, pB1, tB1)
    P1ROW(2, pA2, tA2, pB2, tB2)
    P1ROW(3, pA3, tA3, pB3, tB3)
#undef P1ROW

    __syncthreads();

    // MFMA hblur: wave w owns outtiles O = 8w..8w+7 (16 cols each)
#pragma unroll
    for (int oi = 0; oi < 8; ++oi) {
        const int O = w * 8 + oi;
        unsigned short* dst = feat +
            ((size_t)(img * 32 + O) * 32 + T) * 1024 +
            (quad >> 1) * 512 + n * 8 + (quad & 1) * 4;
#pragma unroll
        for (int f = 0; f < 4; ++f) {
            const short8 af =
                *(const short8*)&featLds[f][n][(2 * O + quad) ^ (n & 7)][0];
            const f32x4 d = __builtin_amdgcn_mfma_f32_16x16x32_bf16(
                af, bw, zc, 0, 0, 0);
            short4v o;
#pragma unroll
            for (int r2 = 0; r2 < 4; ++r2) o[r2] = bf16s(d[r2]);
            *(short4v*)(dst + f * 128) = o;
        }
    }
}

// ======================= PASS 2: vblur + SSIM ===========================
// grid 512 x 256: wave = (img, q strip, stripe); 8-tile LDS ring/wave,
// counted vmcnt, zero barriers in compute.
__global__ __launch_bounds__(256, 2)
void ssim_vpass(const unsigned short* __restrict__ feat,
                float* __restrict__ slotSum, unsigned int* __restrict__ grpCnt,
                unsigned int* __restrict__ finalCnt, float* __restrict__ out) {
    SSIM_W_INIT;
    __shared__ __align__(16) char hbuf[4][16896];   // 16 groups x 1056 B
    __shared__ float wsum[4];

    const int w = threadIdx.x >> 6, L = threadIdx.x & 63;
    const int n = L & 15, quad = L >> 4;
    const int waveId = blockIdx.x * 4 + w;
    const int img = waveId >> 6, rem = waveId & 63;
    const int q = rem >> 5, stripe = rem & 31;
    const int s0 = q << 4;
    char* HB = &hbuf[w][0];

    float S = 0.f;
#pragma unroll
    for (int kk = 0; kk < 11; ++kk) S += bf16f(W[kk]);
    const float c2 = 1.0f / (S * S);
    BW_INIT;
    const f32x4 zc = {0.f, 0.f, 0.f, 0.f};

    const unsigned short* fbase = feat + (size_t)(img * 32 + stripe) * 32768;

    auto issue = [&](int t) {
        const int tc = min(max(t, 0), 31);
        const unsigned short* src = fbase + tc * 1024 + (size_t)L * 8;
        gload16(src, HB + (size_t)((2 * t) & 15) * 1056);
        gload16(src + 512, HB + (size_t)((2 * t + 1) & 15) * 1056);
    };
    auto zfix = [&](int t) {   // overwrite a halo tile's ring slots w/ zeros
        const short8 z = {0, 0, 0, 0, 0, 0, 0, 0};
        *(short8*)(HB + ((2 * t) & 15) * 1056 + L * 16) = z;
        *(short8*)(HB + ((2 * t + 1) & 15) * 1056 + L * 16) = z;
        asm volatile("s_waitcnt lgkmcnt(0)" ::: "memory");
    };

    float lsum = 0.f;
    auto vstep = [&](int s) {
        f32x4 dv[4];
#pragma unroll
        for (int f = 0; f < 4; ++f) {
            const short8 af = *(const short8*)(
                HB + (size_t)((2 * s - 1 + quad) & 15) * 1056 + f * 256 + n * 16);
            dv[f] = __builtin_amdgcn_mfma_f32_16x16x32_bf16(af, bw, zc, 0, 0, 0);
        }
#pragma unroll
        for (int r = 0; r < 4; ++r) {
            const float m1 = dv[0][r] * c2, m2 = dv[1][r] * c2;
            const float Av = dv[2][r] * c2, Bv = dv[3][r] * c2;
            const float m12  = m1 * m2;
            const float smsq = m1 * m1 + m2 * m2;
            const float s12  = __builtin_fmaf(0.25f, Av - Bv, -m12);
            const float s1s2 = __builtin_fmaf(0.5f,  Av + Bv, -smsq);
            const float num = __builtin_fmaf(2.f, m12, 1e-4f) *
                              __builtin_fmaf(2.f, s12, 9e-4f);
            const float den = (smsq + 1e-4f) * (s1s2 + 9e-4f);
            float rc = __builtin_amdgcn_rcpf(den);
            rc = rc * (2.f - den * rc);
            lsum = __builtin_fmaf(num, rc, lsum);
        }
    };

    // prologue: 7 tiles issued (14 insts); land first 3; fix t=-1 if q==0
    issue(s0 - 1); issue(s0); issue(s0 + 1); issue(s0 + 2);
    issue(s0 + 3); issue(s0 + 4); issue(s0 + 5);
    WAITV8;
    if (q == 0) zfix(s0 - 1);

    // steady: ~4 tiles always in flight, counted vmcnt, no barriers
#pragma unroll 1
    for (int s = s0; s <= s0 + 10; ++s) {
        issue(s + 6);            // up to s0+16
        vstep(s);
        WAITV8;                  // lands tile s+2
    }
    vstep(s0 + 11); WAITV6;
    vstep(s0 + 12); WAITV4;
    vstep(s0 + 13); WAITV2;
    vstep(s0 + 14); WAITV0;
    if (q == 1) zfix(s0 + 16);
    vstep(s0 + 15);

    // hierarchical reduce (verbatim r12)
#pragma unroll
    for (int off = 32; off > 0; off >>= 1)
        lsum += __shfl_down(lsum, off, 64);
    if (L == 0) wsum[w] = lsum;
    __syncthreads();
    if (threadIdx.x == 0) {
        const float bs = wsum[0] + wsum[1] + wsum[2] + wsum[3];
        const int g = blockIdx.x & 63;           // 64 groups x 8 blocks
        atomicAdd(&slotSum[g * 16], bs);
        __threadfence();
        if (atomicAdd(&grpCnt[g * 16], 1u) == 7u) {
            __threadfence();
            if (atomicAdd(finalCnt, 1u) == 63u) {
                float s = 0.f;
#pragma unroll
                for (int i = 0; i < 64; ++i)
                    s += atomicAdd(&slotSum[i * 16], 0.f);
                out[0] = 1.0f - s * (1.0f / 8388608.0f);
            }
        }
    }
}

// =================== FALLBACK: r12 monolithic kernel ====================
__global__ __launch_bounds__(256, 2)
void ssim_mono(const float* __restrict__ pred, const float* __restrict__ targ,
               float* __restrict__ slotSum, unsigned int* __restrict__ grpCnt,
               unsigned int* __restrict__ finalCnt, float* __restrict__ out) {
    SSIM_W_INIT;
    __shared__ __align__(16) short hring[4][4][16][72];
    __shared__ float wsum[4];
    extern __shared__ __align__(16) float raw[];

    const int w     = threadIdx.x >> 6;
    const int L     = threadIdx.x & 63;
    const int n     = L & 15;
    const int quad  = L >> 4;
    const int b     = blockIdx.x;
    const int img   = b >> 4;
    const int rem   = b & 15;
    const int q     = rem >> 3;
    const int sst   = rem & 7;
    const int C0    = sst << 6;
    const int c0    = C0 + (w << 4);
    const int s0    = q << 4;
    const bool edge = (c0 == 0) | (c0 == 496);

    const float* __restrict__ pim = pred + (size_t)img * 262144;
    const float* __restrict__ tim = targ + (size_t)img * 262144;

    float S = 0.f;
#pragma unroll
    for (int kk = 0; kk < 11; ++kk) S += bf16f(W[kk]);
    const float c2 = 1.0f / (S * S);
    BW_INIT;
    const f32x4 zc = {0.f, 0.f, 0.f, 0.f};

    const int tsel  = w >> 1;
    const int pbase = (w & 1) * 4;
    const float* __restrict__ imw = tsel ? tim : pim;
    int rho_[4], col_[4];
#pragma unroll
    for (int j = 0; j < 4; ++j) {
        const int rho = 2 * (pbase + j) + (L >> 5);
        const int gs  = (L & 31) ^ ((2 * j + (L >> 5)) & 7);
        rho_[j] = rho;
        col_[j] = min(max(C0 - 32 + 4 * gs, 0), 508);
    }
    const int gA = (6 + 4 * w + 2 * quad) ^ (n & 7);
    const int gB = (7 + 4 * w + 2 * quad) ^ (n & 7);
    const int cb = c0 - 8 + quad * 8;
    const bool ok0 = (unsigned)cb < 512u;
    const bool ok1 = (unsigned)(cb + 4) < 512u;

    float lsum = 0.f;
    auto issue = [&](int Ts) {
        const int slot = Ts & 1;
        float* dbase = raw + slot * 4096 + tsel * 2048 + 2 * pbase * 128;
#pragma unroll
        for (int j = 0; j < 4; ++j) {
            const int grow = min(max(16 * Ts + rho_[j], 0), 511);
            gload16(imw + grow * 512 + col_[j], dbase + j * 256);
        }
    };
    auto hproc = [&](int Tt) {
        const int wslot = ((Tt << 4) & 63) + quad * 4;
        short4v o[4];
        if ((unsigned)Tt > 31u) {
#pragma unroll
            for (int f = 0; f < 4; ++f) o[f] = (short4v){0, 0, 0, 0};
        } else {
            const float* bp = raw + (Tt & 1) * 4096 + n * 128;
            const float* bt = bp + 2048;
            f32x4 p0 = *(const f32x4*)(bp + gA * 4);
            f32x4 p1 = *(const f32x4*)(bp + gB * 4);
            f32x4 t0 = *(const f32x4*)(bt + gA * 4);
            f32x4 t1 = *(const f32x4*)(bt + gB * 4);
            if (edge) {
                p0 = ok0 ? p0 : zc;  p1 = ok1 ? p1 : zc;
                t0 = ok0 ? t0 : zc;  t1 = ok1 ? t1 : zc;
            }
            short8 fa[4];
#pragma unroll
            for (int j = 0; j < 4; ++j) {
                const float pj = p0[j], tj = t0[j];
                const float u = pj + tj, v = pj - tj;
                fa[0][j] = bf16s(pj); fa[1][j] = bf16s(tj);
                fa[2][j] = bf16s(u * u); fa[3][j] = bf16s(v * v);
            }
#pragma unroll
            for (int j = 0; j < 4; ++j) {
                const float pj = p1[j], tj = t1[j];
                const float u = pj + tj, v = pj - tj;
                fa[0][j + 4] = bf16s(pj); fa[1][j + 4] = bf16s(tj);
                fa[2][j + 4] = bf16s(u * u); fa[3][j + 4] = bf16s(v * v);
            }
#pragma unroll
            for (int f = 0; f < 4; ++f) {
                const f32x4 d = __builtin_amdgcn_mfma_f32_16x16x32_bf16(
                    fa[f], bw, zc, 0, 0, 0);
                short4v ov;
#pragma unroll
                for (int r2 = 0; r2 < 4; ++r2) ov[r2] = bf16s(d[r2]);
                o[f] = ov;
            }
        }
#pragma unroll
        for (int f = 0; f < 4; ++f)
            *(short4v*)&hring[w][f][n][wslot] = o[f];
    };
    auto vstep = [&](int s) {
        const int rslot0 = (int)(((unsigned)((s << 4) - 8)) & 63u);
        const int chunk  = (rslot0 + quad * 8) & 63;
        f32x4 dv[4];
#pragma unroll
        for (int f = 0; f < 4; ++f) {
            const short8 af = *(const short8*)&hring[w][f][n][chunk];
            dv[f] = __builtin_amdgcn_mfma_f32_16x16x32_bf16(af, bw, zc, 0, 0, 0);
        }
#pragma unroll
        for (int r = 0; r < 4; ++r) {
            const float m1 = dv[0][r] * c2, m2 = dv[1][r] * c2;
            const float Av = dv[2][r] * c2, Bv = dv[3][r] * c2;
            const float m12  = m1 * m2;
            const float smsq = m1 * m1 + m2 * m2;
            const float s12  = __builtin_fmaf(0.25f, Av - Bv, -m12);
            const float s1s2 = __builtin_fmaf(0.5f,  Av + Bv, -smsq);
            const float num = __builtin_fmaf(2.f, m12, 1e-4f) *
                              __builtin_fmaf(2.f, s12, 9e-4f);
            const float den = (smsq + 1e-4f) * (s1s2 + 9e-4f);
            float rc = __builtin_amdgcn_rcpf(den);
            rc = rc * (2.f - den * rc);
            lsum = __builtin_fmaf(num, rc, lsum);
        }
    };

#define BAR   __builtin_amdgcn_s_barrier()
#define LGK0  asm volatile("s_waitcnt lgkmcnt(0)" ::: "memory")
    issue(s0 - 1); issue(s0);
    WAITV4; BAR; hproc(s0 - 1);
    LGK0;  BAR; issue(s0 + 1);
    WAITV4; BAR; hproc(s0);
    LGK0;  BAR; issue(s0 + 2);
    WAITV4; BAR; hproc(s0 + 1);
    LGK0;  BAR; issue(s0 + 3);
#pragma unroll 1
    for (int s = s0; s < s0 + 15; ++s) {
        vstep(s);
        if (s <= s0 + 13) { WAITV4; } else { WAITV0; }
        BAR;
        hproc(s + 2);
        LGK0; BAR;
        if (s + 4 <= s0 + 16) issue(s + 4);
    }
    vstep(s0 + 15);
#undef BAR
#undef LGK0

#pragma unroll
    for (int off = 32; off > 0; off >>= 1)
        lsum += __shfl_down(lsum, off, 64);
    if (L == 0) wsum[w] = lsum;
    __syncthreads();
    if (threadIdx.x == 0) {
        const float bs = wsum[0] + wsum[1] + wsum[2] + wsum[3];
        const int g = blockIdx.x & 63;
        atomicAdd(&slotSum[g * 16], bs);
        __threadfence();
        if (atomicAdd(&grpCnt[g * 16], 1u) == 7u) {
            __threadfence();
            if (atomicAdd(finalCnt, 1u) == 63u) {
                float s = 0.f;
#pragma unroll
                for (int i = 0; i < 64; ++i)
                    s += atomicAdd(&slotSum[i * 16], 0.f);
                out[0] = 1.0f - s * (1.0f / 8388608.0f);
            }
        }
    }
}

extern "C" void kernel_launch(void* const* d_in, const int* in_sizes, int n_in,
                              void* d_out, int out_size, void* d_ws,
                              size_t ws_size, hipStream_t stream) {
    const float* pred = (const float*)d_in[0];
    const float* targ = (const float*)d_in[1];
    // ws: [0,4096) slotSum @64B stride; [4096,8192) grpCnt; [8192,8196)
    // finalCnt; [65536, 65536+64MB) feat intermediate (two-pass path).
    float* slotSum = (float*)d_ws;
    unsigned int* grpCnt = (unsigned int*)((char*)d_ws + 4096);
    unsigned int* finalCnt = (unsigned int*)((char*)d_ws + 8192);

    hipMemsetAsync(d_ws, 0, 8196, stream);
    const size_t featBytes = 32ull * 32 * 32 * 2048;   // 64 MiB
    if (ws_size >= 65536 + featBytes) {
        unsigned short* feat = (unsigned short*)((char*)d_ws + 65536);
        ssim_hblur<<<dim3(1024), dim3(256), 0, stream>>>(pred, targ, feat);
        ssim_vpass<<<dim3(512), dim3(256), 0, stream>>>(feat, slotSum, grpCnt,
                                                        finalCnt, (float*)d_out);
    } else {
        ssim_mono<<<dim3(512), dim3(256), 32768, stream>>>(pred, targ, slotSum,
                                                           grpCnt, finalCnt,
                                                           (float*)d_out);
    }
    (void)in_sizes; (void)n_in; (void)out_size; (void)ws_size;
}